// Round 6
// baseline (90.234 us; speedup 1.0000x reference)
//
#include <hip/hip_runtime.h>
#include <hip/hip_bf16.h>

#define CC 128   // channels
#define HH 128   // hidden
#define NB 8     // nodes per block iteration (DEG=16 rows each)

typedef __attribute__((ext_vector_type(8))) _Float16 half8;
typedef __attribute__((ext_vector_type(2))) _Float16 half2v;
typedef __attribute__((ext_vector_type(2))) __fp16   fp16x2;
typedef __attribute__((ext_vector_type(4))) float f32x4;

union H2U { half2v h; fp16x2 g; unsigned int u; };

__device__ __forceinline__ unsigned int pkrtz(float a, float b) {
    H2U v; v.g = __builtin_amdgcn_cvt_pkrtz(a, b); return v.u;
}

// gelu via tanh form: 0.5x(1+tanh(0.79788456(x+0.044715x^3))), max err ~3e-4.
// gelu = x*(1 - 1/(1+e^{2y})) -- 8 VALU ops (2 trans), saturates correctly.
__device__ __forceinline__ float gelu_f(float x) {
    float x2 = x * x;
    float t  = fmaf(0.044715f, x2, 1.0f);
    float a  = x * t;
    float e  = __builtin_amdgcn_exp2f(a * 2.3022092f);
    float r  = __builtin_amdgcn_rcpf(e + 1.0f);
    return fmaf(-x, r, x);
}

// fp32 -> f16 repack of in_features into workspace.
__global__ __launch_bounds__(256)
void f32_to_f16_kernel(const float* __restrict__ in,
                       _Float16* __restrict__ out, long n8) {
    long i = (long)blockIdx.x * blockDim.x + threadIdx.x;
    const long stride = (long)gridDim.x * blockDim.x;
    for (; i < n8; i += stride) {
        const float4* p = reinterpret_cast<const float4*>(in) + i * 2;
        float4 a = p[0], b = p[1];
        half8 o;
        o[0] = (_Float16)a.x; o[1] = (_Float16)a.y;
        o[2] = (_Float16)a.z; o[3] = (_Float16)a.w;
        o[4] = (_Float16)b.x; o[5] = (_Float16)b.y;
        o[6] = (_Float16)b.z; o[7] = (_Float16)b.w;
        *reinterpret_cast<half8*>(out + i * 8) = o;
    }
}

// Block = 512 threads = 8 waves; NB=8 nodes per group. All f16.
// prefetch (pre-barrier): per-wave node ids via 2x dwordx4 from nbr (uniform
//   row_splits), then 8x dwordx4 f16 feature gathers into regs (T14).
// phase 0: threads 0-127 stage agg rows (f16, K-pad to 8).
// phase 1: pre^T = mfma(w1frag, aggfrag) with C-init = b1; unconditional
//   broadcast agg load (kgrp>=1 lanes multiply by w1frag=0); gelu; packed
//   b64 write to XOR-swizzled hb.
// phase 2a: msg^T = mfma(W2frag, hfrag) with C-init = b2; packed b64 write.
// phase 2b: lane=(batch, ehalf, cchunk), wave=node: uniform dg==16 fast path,
//   8x (b128 msg ds_read x reg g, 4x v_pk_fma_f16); shfl-reduce; mean; f32x4
//   stores.
template<bool F16G>
__global__ __launch_bounds__(512, 4)
void nmlp_kernel(const float* __restrict__ x_in,
                 const float* __restrict__ x_out,
                 const float* __restrict__ in_feat,
                 const _Float16* __restrict__ gws,
                 const int* __restrict__ nbr,
                 const int* __restrict__ row_splits,
                 const float* __restrict__ W1,
                 const float* __restrict__ b1,
                 const float* __restrict__ W2,
                 const float* __restrict__ b2,
                 float* __restrict__ out,
                 int N, int M)
{
    // byte ^= (row&7)<<4 swizzle on 16B chunks within each 256B row (G4).
    __shared__ __align__(16) char hb[NB * 16 * 256];    // 32 KB h (f16)
    __shared__ __align__(16) char msgb[NB * 16 * 256];  // 32 KB msg (f16)
    __shared__ __align__(16) char aggb[NB * 16 * 16];   // 2 KB agg rows

    const int tid  = threadIdx.x;
    const int lane = tid & 63;
    const int wave = tid >> 6;        // 0..7
    const int cbase = wave * 16;      // channel tile (W1/W2 N-dim)
    const int l15  = lane & 15;
    const int kgrp = lane >> 4;       // 0..3

    // W1 A-frag: A[hk_local=l15][k=kgrp*8+i], zero-pad k>=6
    half8 w1frag;
    #pragma unroll
    for (int i = 0; i < 8; ++i) {
        int k = kgrp*8 + i;
        w1frag[i] = (k < 6) ? (_Float16)W1[k*HH + cbase + l15] : (_Float16)0.f;
    }
    // W2 A-frags: A[c_local=l15][k=kb*32+kgrp*8+i]
    half8 bfrag[4];
    #pragma unroll
    for (int kb = 0; kb < 4; ++kb)
        #pragma unroll
        for (int i = 0; i < 8; ++i) {
            int k = kb*32 + kgrp*8 + i;
            bfrag[kb][i] = (_Float16)W2[k*CC + cbase + l15];
        }
    // biases for the 4 output-channel rows held by this thread
    float b1v[4], b2v[4];
    #pragma unroll
    for (int i = 0; i < 4; ++i) {
        b1v[i] = b1[cbase + kgrp*4 + i];
        b2v[i] = b2[cbase + kgrp*4 + i];
    }

    const _Float16* g0p = gws;
    const _Float16* g1p = gws + (size_t)N * CC;
    const float* f0p = in_feat;
    const float* f1p = in_feat + (size_t)N * CC;

    const int arow_off = l15 * 256;        // phase-2a h row (edge)
    const int aswz = (l15 & 7) << 4;
    const int wcol_off = (cbase + kgrp*4) * 2;   // packed write byte offset

    // phase-2b identity
    const int bb     = lane >> 5;          // batch 0/1
    const int ehalf  = (lane >> 4) & 1;    // edge half
    const int cchunk = lane & 15;          // 8-channel chunk
    const _Float16* gpb = bb ? g1p : g0p;

    const int ngroups = (M + NB - 1) / NB;
    for (int g = blockIdx.x; g < ngroups; g += gridDim.x) {
        const int m0 = g * NB;
        const int mw = m0 + wave;          // this wave's phase-2b node

        // ---- prefetch: ids (direct from nbr) + feature gathers ----
        int sW = 0, dgv = 0;
        if (mw < M) { sW = row_splits[mw]; dgv = row_splits[mw+1] - sW; }
        const int dgs = __builtin_amdgcn_readfirstlane(dgv);
        int ids8[8];
        if (dgs == 16 && ((sW & 3) == 0)) {
            const int4 ia = *reinterpret_cast<const int4*>(nbr + sW + ehalf*8);
            const int4 ib = *reinterpret_cast<const int4*>(nbr + sW + ehalf*8 + 4);
            ids8[0]=ia.x; ids8[1]=ia.y; ids8[2]=ia.z; ids8[3]=ia.w;
            ids8[4]=ib.x; ids8[5]=ib.y; ids8[6]=ib.z; ids8[7]=ib.w;
        } else {
            #pragma unroll
            for (int e8 = 0; e8 < 8; ++e8) {
                const int e = ehalf*8 + e8;
                ids8[e8] = (e < dgs) ? nbr[sW + e] : 0;
            }
        }
        uint4 gv[8];
        if (F16G) {
            const _Float16* gcp = gpb + cchunk*8;
            #pragma unroll
            for (int e8 = 0; e8 < 8; ++e8)
                gv[e8] = *reinterpret_cast<const uint4*>(
                    gcp + (size_t)ids8[e8]*CC);
        }

        // ---- phase 0: agg rows ----
        if (tid < NB*16) {
            const int r = tid >> 4, e = tid & 15;
            const int m = m0 + r;
            int id = 0; int dg = 0;
            if (m < M) { int s = row_splits[m]; dg = row_splits[m+1] - s;
                         if (e < dg) id = nbr[s + e]; }
            const bool valid = (m < M) && (e < dg);
            float a0=0.f,a1=0.f,a2=0.f,a3=0.f,a4=0.f,a5=0.f;
            if (valid) {
                a0 = x_in[id*3+0]; a1 = x_in[id*3+1]; a2 = x_in[id*3+2];
                a3 = x_out[m*3+0]; a4 = x_out[m*3+1]; a5 = x_out[m*3+2];
            }
            uint4 pk;
            pk.x = pkrtz(a0, a1);
            pk.y = pkrtz(a2, a3);
            pk.z = pkrtz(a4, a5);
            pk.w = 0u;
            *reinterpret_cast<uint4*>(&aggb[tid*16]) = pk;
        }
        __syncthreads();

        // ---- phase 1: pre^T = mfma(W1frag, aggfrag) + b1 -> gelu -> hb ----
        #pragma unroll
        for (int r = 0; r < NB; ++r) {
            // broadcast load; kgrp>=1 lanes' values multiply w1frag==0
            half8 af = *reinterpret_cast<const half8*>(&aggb[(r*16 + l15)*16]);
            f32x4 pa = {b1v[0], b1v[1], b1v[2], b1v[3]};   // bias as C-init
            pa = __builtin_amdgcn_mfma_f32_16x16x32_f16(w1frag, af, pa, 0, 0, 0);
            float g0 = gelu_f(pa[0]);
            float g1 = gelu_f(pa[1]);
            float g2 = gelu_f(pa[2]);
            float g3 = gelu_f(pa[3]);
            uint2 w = make_uint2(pkrtz(g0, g1), pkrtz(g2, g3));
            *reinterpret_cast<uint2*>(
                hb + r*4096 + l15*256 + (wcol_off ^ aswz)) = w;
        }
        __syncthreads();

        // ---- phase 2a: msg^T = mfma(W2frag, hfrag) + b2 -> msgb ----
        #pragma unroll
        for (int r = 0; r < NB; ++r) {
            f32x4 a = {b2v[0], b2v[1], b2v[2], b2v[3]};    // bias as C-init
            const char* base = hb + r*4096 + arow_off;
            #pragma unroll
            for (int kb = 0; kb < 4; ++kb) {
                half8 hf = *reinterpret_cast<const half8*>(
                    base + ((kb*64 + kgrp*16) ^ aswz));
                a = __builtin_amdgcn_mfma_f32_16x16x32_f16(bfrag[kb], hf, a, 0, 0, 0);
            }
            uint2 w = make_uint2(pkrtz(a[0], a[1]), pkrtz(a[2], a[3]));
            *reinterpret_cast<uint2*>(
                msgb + r*4096 + l15*256 + (wcol_off ^ aswz)) = w;
        }
        __syncthreads();

        // ---- phase 2b: weighted segment mean (packed f16 fma) ----
        if (mw < M) {
            half2v o0 = {0,0}, o1 = {0,0}, o2 = {0,0}, o3 = {0,0};
            const char* mbase = msgb + wave*4096;
            if (dgs == 16) {              // uniform fast path (no guards)
                #pragma unroll
                for (int e8 = 0; e8 < 8; ++e8) {
                    const int e = ehalf*8 + e8;
                    const uint4 mv = *reinterpret_cast<const uint4*>(
                        mbase + e*256 + ((cchunk*16) ^ ((e & 7) << 4)));
                    const uint4 gvv = F16G ? gv[e8] : uint4{0,0,0,0};
                    uint4 gq = gvv;
                    if (!F16G) {
                        const float* fp = bb ? f1p : f0p;
                        const float4* q = reinterpret_cast<const float4*>(
                            fp + (size_t)ids8[e8]*CC + cchunk*8);
                        float4 qa = q[0], qb = q[1];
                        gq.x = pkrtz(qa.x, qa.y); gq.y = pkrtz(qa.z, qa.w);
                        gq.z = pkrtz(qb.x, qb.y); gq.w = pkrtz(qb.z, qb.w);
                    }
                    H2U ma, ga;
                    ma.u = mv.x; ga.u = gq.x; o0 += ma.h * ga.h;
                    ma.u = mv.y; ga.u = gq.y; o1 += ma.h * ga.h;
                    ma.u = mv.z; ga.u = gq.z; o2 += ma.h * ga.h;
                    ma.u = mv.w; ga.u = gq.w; o3 += ma.h * ga.h;
                }
            } else {
                #pragma unroll
                for (int e8 = 0; e8 < 8; ++e8) {
                    const int e = ehalf*8 + e8;
                    if (e < dgs) {
                        const uint4 mv = *reinterpret_cast<const uint4*>(
                            mbase + e*256 + ((cchunk*16) ^ ((e & 7) << 4)));
                        uint4 gq;
                        if (F16G) gq = gv[e8];
                        else {
                            const float* fp = bb ? f1p : f0p;
                            const float4* q = reinterpret_cast<const float4*>(
                                fp + (size_t)ids8[e8]*CC + cchunk*8);
                            float4 qa = q[0], qb = q[1];
                            gq.x = pkrtz(qa.x, qa.y); gq.y = pkrtz(qa.z, qa.w);
                            gq.z = pkrtz(qb.x, qb.y); gq.w = pkrtz(qb.z, qb.w);
                        }
                        H2U ma, ga;
                        ma.u = mv.x; ga.u = gq.x; o0 += ma.h * ga.h;
                        ma.u = mv.y; ga.u = gq.y; o1 += ma.h * ga.h;
                        ma.u = mv.z; ga.u = gq.z; o2 += ma.h * ga.h;
                        ma.u = mv.w; ga.u = gq.w; o3 += ma.h * ga.h;
                    }
                }
            }
            // reduce over ehalf partner (lane ^ 16), still packed f16
            H2U u0, u1, u2, u3, p;
            u0.h = o0; u1.h = o1; u2.h = o2; u3.h = o3;
            p.u = (unsigned int)__shfl_xor((int)u0.u, 16); u0.h += p.h;
            p.u = (unsigned int)__shfl_xor((int)u1.u, 16); u1.h += p.h;
            p.u = (unsigned int)__shfl_xor((int)u2.u, 16); u2.h += p.h;
            p.u = (unsigned int)__shfl_xor((int)u3.u, 16); u3.h += p.h;
            if (ehalf == 0) {
                const float invd = (dgs == 16) ? 0.0625f
                                 : 1.f / (float)(dgs > 0 ? dgs : 1);
                float* op = out + (size_t)bb*M*CC + (size_t)mw*CC + cchunk*8;
                float4 v0 = {(float)u0.h[0]*invd, (float)u0.h[1]*invd,
                             (float)u1.h[0]*invd, (float)u1.h[1]*invd};
                float4 v1 = {(float)u2.h[0]*invd, (float)u2.h[1]*invd,
                             (float)u3.h[0]*invd, (float)u3.h[1]*invd};
                *reinterpret_cast<float4*>(op)     = v0;
                *reinterpret_cast<float4*>(op + 4) = v1;
            }
        }
        __syncthreads();  // protect LDS before next group
    }
}

extern "C" void kernel_launch(void* const* d_in, const int* in_sizes, int n_in,
                              void* d_out, int out_size, void* d_ws, size_t ws_size,
                              hipStream_t stream) {
    const float* x_in    = (const float*)d_in[0];
    const float* x_out   = (const float*)d_in[1];
    const float* in_feat = (const float*)d_in[2];
    const int*   nbr     = (const int*)d_in[3];
    const int*   rs      = (const int*)d_in[4];
    const float* W1      = (const float*)d_in[5];
    const float* b1      = (const float*)d_in[6];
    const float* W2      = (const float*)d_in[7];
    const float* b2      = (const float*)d_in[8];
    float* out = (float*)d_out;

    const int N = in_sizes[0] / 3;
    const int M = in_sizes[1] / 3;

    const int ngroups = (M + NB - 1) / NB;
    int grid = ngroups < 512 ? ngroups : 512;   // persistent: 2 blocks/CU

    const size_t nfeat = (size_t)2 * N * CC;    // B=2 per reference
    const bool use_f16 = (ws_size >= nfeat * sizeof(_Float16)) &&
                         (nfeat % 8 == 0);
    if (use_f16) {
        const long n8 = (long)(nfeat / 8);
        int cgrid = (int)((n8 + 255) / 256);
        if (cgrid > 4096) cgrid = 4096;
        f32_to_f16_kernel<<<cgrid, 256, 0, stream>>>(
            in_feat, (_Float16*)d_ws, n8);
        nmlp_kernel<true><<<grid, 512, 0, stream>>>(
            x_in, x_out, in_feat, (const _Float16*)d_ws,
            nbr, rs, W1, b1, W2, b2, out, N, M);
    } else {
        nmlp_kernel<false><<<grid, 512, 0, stream>>>(
            x_in, x_out, in_feat, nullptr,
            nbr, rs, W1, b1, W2, b2, out, N, M);
    }
}

// Round 7
// 87.458 us; speedup vs baseline: 1.0317x; 1.0317x over previous
//
#include <hip/hip_runtime.h>
#include <hip/hip_bf16.h>

#define CC 128   // channels
#define HH 128   // hidden
#define NB 4     // nodes per block iteration (DEG=16 rows each)

typedef __attribute__((ext_vector_type(8))) _Float16 half8;
typedef __attribute__((ext_vector_type(2))) _Float16 half2v;
typedef __attribute__((ext_vector_type(2))) __fp16   fp16x2;
typedef __attribute__((ext_vector_type(4))) float f32x4;

union H2U { half2v h; fp16x2 g; unsigned int u; };

__device__ __forceinline__ unsigned int pkrtz(float a, float b) {
    H2U v; v.g = __builtin_amdgcn_cvt_pkrtz(a, b); return v.u;
}

// gelu via tanh form: 0.5x(1+tanh(0.79788456(x+0.044715x^3))), max err ~3e-4.
__device__ __forceinline__ float gelu_f(float x) {
    float x2 = x * x;
    float t  = fmaf(0.044715f, x2, 1.0f);
    float a  = x * t;
    float e  = __builtin_amdgcn_exp2f(a * 2.3022092f);
    float r  = __builtin_amdgcn_rcpf(e + 1.0f);
    return fmaf(-x, r, x);
}

// fp32 -> f16 repack of in_features into workspace.
__global__ __launch_bounds__(256)
void f32_to_f16_kernel(const float* __restrict__ in,
                       _Float16* __restrict__ out, long n8) {
    long i = (long)blockIdx.x * blockDim.x + threadIdx.x;
    const long stride = (long)gridDim.x * blockDim.x;
    for (; i < n8; i += stride) {
        const float4* p = reinterpret_cast<const float4*>(in) + i * 2;
        float4 a = p[0], b = p[1];
        half8 o;
        o[0] = (_Float16)a.x; o[1] = (_Float16)a.y;
        o[2] = (_Float16)a.z; o[3] = (_Float16)a.w;
        o[4] = (_Float16)b.x; o[5] = (_Float16)b.y;
        o[6] = (_Float16)b.z; o[7] = (_Float16)b.w;
        *reinterpret_cast<half8*>(out + i * 8) = o;
    }
}

// Block = 256 threads = 4 waves; NB=4 nodes per group. All f16.
// Each wave owns TWO 16-col tiles (32 cols): one A-frag read feeds 2 MFMAs
// (halves phase-2a LDS traffic vs 8-wave/1-tile). 33 KB LDS -> 4 blocks/CU
// (4 decorrelated barrier domains). 3 barriers/group (trailing barrier
// provably redundant: next-group writers are ordered by earlier barriers).
template<bool F16G>
__global__ __launch_bounds__(256, 4)
void nmlp_kernel(const float* __restrict__ x_in,
                 const float* __restrict__ x_out,
                 const float* __restrict__ in_feat,
                 const _Float16* __restrict__ gws,
                 const int* __restrict__ nbr,
                 const int* __restrict__ row_splits,
                 const float* __restrict__ W1,
                 const float* __restrict__ b1,
                 const float* __restrict__ W2,
                 const float* __restrict__ b2,
                 float* __restrict__ out,
                 int N, int M)
{
    // byte ^= (row&7)<<4 swizzle on 16B chunks within each 256B row (G4).
    __shared__ __align__(16) char hb[NB * 16 * 256];    // 16 KB h (f16)
    __shared__ __align__(16) char msgb[NB * 16 * 256];  // 16 KB msg (f16)
    __shared__ __align__(16) char aggb[NB * 16 * 16];   // 1 KB agg rows

    const int tid  = threadIdx.x;
    const int lane = tid & 63;
    const int wave = tid >> 6;        // 0..3 (= node in phase 2b)
    const int l15  = lane & 15;
    const int kgrp = lane >> 4;       // 0..3

    // two 16-col tiles per wave: tile tt -> cols [(2*wave+tt)*16, +16)
    // W1 A-frags: A[hk_local=l15][k=kgrp*8+i], zero-pad k>=6
    half8 w1frag[2];
    // W2 A-frags: A[c_local=l15][k=kb*32+kgrp*8+i]
    half8 bfrag[2][4];
    float b1v[2][4], b2v[2][4];
    #pragma unroll
    for (int tt = 0; tt < 2; ++tt) {
        const int cb = (2*wave + tt) * 16;
        #pragma unroll
        for (int i = 0; i < 8; ++i) {
            int k = kgrp*8 + i;
            w1frag[tt][i] = (k < 6) ? (_Float16)W1[k*HH + cb + l15]
                                    : (_Float16)0.f;
        }
        #pragma unroll
        for (int kb = 0; kb < 4; ++kb)
            #pragma unroll
            for (int i = 0; i < 8; ++i) {
                int k = kb*32 + kgrp*8 + i;
                bfrag[tt][kb][i] = (_Float16)W2[k*CC + cb + l15];
            }
        #pragma unroll
        for (int i = 0; i < 4; ++i) {
            b1v[tt][i] = b1[cb + kgrp*4 + i];
            b2v[tt][i] = b2[cb + kgrp*4 + i];
        }
    }

    const _Float16* g0p = gws;
    const _Float16* g1p = gws + (size_t)N * CC;
    const float* f0p = in_feat;
    const float* f1p = in_feat + (size_t)N * CC;

    const int aswz = (l15 & 7) << 4;
    const int wrow_off = l15 * 256;

    // phase-2b identity
    const int bb     = lane >> 5;          // batch 0/1
    const int ehalf  = (lane >> 4) & 1;    // edge half
    const int cchunk = lane & 15;          // 8-channel chunk
    const _Float16* gpb = bb ? g1p : g0p;

    const int ngroups = (M + NB - 1) / NB;
    for (int g = blockIdx.x; g < ngroups; g += gridDim.x) {
        const int m0 = g * NB;
        const int mw = m0 + wave;          // this wave's phase-2b node

        // ---- prefetch: ids (direct from nbr) + feature gathers (T14) ----
        int sW = 0, dgv = 0;
        if (mw < M) { sW = row_splits[mw]; dgv = row_splits[mw+1] - sW; }
        const int dgs = __builtin_amdgcn_readfirstlane(dgv);
        int ids8[8];
        if (dgs == 16 && ((sW & 3) == 0)) {
            const int4 ia = *reinterpret_cast<const int4*>(nbr + sW + ehalf*8);
            const int4 ib = *reinterpret_cast<const int4*>(nbr + sW + ehalf*8 + 4);
            ids8[0]=ia.x; ids8[1]=ia.y; ids8[2]=ia.z; ids8[3]=ia.w;
            ids8[4]=ib.x; ids8[5]=ib.y; ids8[6]=ib.z; ids8[7]=ib.w;
        } else {
            #pragma unroll
            for (int e8 = 0; e8 < 8; ++e8) {
                const int e = ehalf*8 + e8;
                ids8[e8] = (e < dgs) ? nbr[sW + e] : 0;
            }
        }
        uint4 gv[8];
        if (F16G) {
            const _Float16* gcp = gpb + cchunk*8;
            #pragma unroll
            for (int e8 = 0; e8 < 8; ++e8)
                gv[e8] = *reinterpret_cast<const uint4*>(
                    gcp + (size_t)ids8[e8]*CC);
        }

        // ---- phase 0: agg rows (wave 0 stages all NB*16 edges) ----
        if (tid < NB*16) {
            const int r = tid >> 4, e = tid & 15;
            const int m = m0 + r;
            int id = 0; int dg = 0;
            if (m < M) { int s = row_splits[m]; dg = row_splits[m+1] - s;
                         if (e < dg) id = nbr[s + e]; }
            const bool valid = (m < M) && (e < dg);
            float a0=0.f,a1=0.f,a2=0.f,a3=0.f,a4=0.f,a5=0.f;
            if (valid) {
                a0 = x_in[id*3+0]; a1 = x_in[id*3+1]; a2 = x_in[id*3+2];
                a3 = x_out[m*3+0]; a4 = x_out[m*3+1]; a5 = x_out[m*3+2];
            }
            uint4 pk;
            pk.x = pkrtz(a0, a1);
            pk.y = pkrtz(a2, a3);
            pk.z = pkrtz(a4, a5);
            pk.w = 0u;
            *reinterpret_cast<uint4*>(&aggb[tid*16]) = pk;
        }
        __syncthreads();

        // ---- phase 1: pre^T = mfma(W1frag, aggfrag) + b1 -> gelu -> hb ----
        #pragma unroll
        for (int r = 0; r < NB; ++r) {
            // broadcast load; kgrp>=1 lanes' values multiply w1frag==0
            half8 af = *reinterpret_cast<const half8*>(&aggb[(r*16 + l15)*16]);
            #pragma unroll
            for (int tt = 0; tt < 2; ++tt) {
                f32x4 pa = {b1v[tt][0], b1v[tt][1], b1v[tt][2], b1v[tt][3]};
                pa = __builtin_amdgcn_mfma_f32_16x16x32_f16(w1frag[tt], af, pa, 0, 0, 0);
                float g0 = gelu_f(pa[0]);
                float g1 = gelu_f(pa[1]);
                float g2 = gelu_f(pa[2]);
                float g3 = gelu_f(pa[3]);
                const int c0 = (2*wave + tt)*16 + kgrp*4;
                uint2 w = make_uint2(pkrtz(g0, g1), pkrtz(g2, g3));
                *reinterpret_cast<uint2*>(
                    hb + r*4096 + wrow_off + ((c0*2) ^ aswz)) = w;
            }
        }
        __syncthreads();

        // ---- phase 2a: msg^T = mfma(W2frag, hfrag) + b2 -> msgb ----
        #pragma unroll
        for (int r = 0; r < NB; ++r) {
            f32x4 a0c = {b2v[0][0], b2v[0][1], b2v[0][2], b2v[0][3]};
            f32x4 a1c = {b2v[1][0], b2v[1][1], b2v[1][2], b2v[1][3]};
            const char* base = hb + r*4096 + wrow_off;
            #pragma unroll
            for (int kb = 0; kb < 4; ++kb) {
                // ONE A-frag read feeds both col-tiles' MFMAs
                half8 hf = *reinterpret_cast<const half8*>(
                    base + ((kb*64 + kgrp*16) ^ aswz));
                a0c = __builtin_amdgcn_mfma_f32_16x16x32_f16(bfrag[0][kb], hf, a0c, 0, 0, 0);
                a1c = __builtin_amdgcn_mfma_f32_16x16x32_f16(bfrag[1][kb], hf, a1c, 0, 0, 0);
            }
            const int c0 = 2*wave*16 + kgrp*4;
            uint2 w0 = make_uint2(pkrtz(a0c[0], a0c[1]), pkrtz(a0c[2], a0c[3]));
            uint2 w1 = make_uint2(pkrtz(a1c[0], a1c[1]), pkrtz(a1c[2], a1c[3]));
            *reinterpret_cast<uint2*>(
                msgb + r*4096 + wrow_off + ((c0*2) ^ aswz)) = w0;
            *reinterpret_cast<uint2*>(
                msgb + r*4096 + wrow_off + (((c0+16)*2) ^ aswz)) = w1;
        }
        __syncthreads();

        // ---- phase 2b: weighted segment mean (packed f16 fma) ----
        if (mw < M) {
            half2v o0 = {0,0}, o1 = {0,0}, o2 = {0,0}, o3 = {0,0};
            const char* mbase = msgb + wave*4096;
            if (dgs == 16) {              // uniform fast path (no guards)
                #pragma unroll
                for (int e8 = 0; e8 < 8; ++e8) {
                    const int e = ehalf*8 + e8;
                    const uint4 mv = *reinterpret_cast<const uint4*>(
                        mbase + e*256 + ((cchunk*16) ^ ((e & 7) << 4)));
                    uint4 gq = F16G ? gv[e8] : uint4{0,0,0,0};
                    if (!F16G) {
                        const float* fp = bb ? f1p : f0p;
                        const float4* q = reinterpret_cast<const float4*>(
                            fp + (size_t)ids8[e8]*CC + cchunk*8);
                        float4 qa = q[0], qb = q[1];
                        gq.x = pkrtz(qa.x, qa.y); gq.y = pkrtz(qa.z, qa.w);
                        gq.z = pkrtz(qb.x, qb.y); gq.w = pkrtz(qb.z, qb.w);
                    }
                    H2U ma, ga;
                    ma.u = mv.x; ga.u = gq.x; o0 += ma.h * ga.h;
                    ma.u = mv.y; ga.u = gq.y; o1 += ma.h * ga.h;
                    ma.u = mv.z; ga.u = gq.z; o2 += ma.h * ga.h;
                    ma.u = mv.w; ga.u = gq.w; o3 += ma.h * ga.h;
                }
            } else {
                #pragma unroll
                for (int e8 = 0; e8 < 8; ++e8) {
                    const int e = ehalf*8 + e8;
                    if (e < dgs) {
                        const uint4 mv = *reinterpret_cast<const uint4*>(
                            mbase + e*256 + ((cchunk*16) ^ ((e & 7) << 4)));
                        uint4 gq;
                        if (F16G) gq = gv[e8];
                        else {
                            const float* fp = bb ? f1p : f0p;
                            const float4* q = reinterpret_cast<const float4*>(
                                fp + (size_t)ids8[e8]*CC + cchunk*8);
                            float4 qa = q[0], qb = q[1];
                            gq.x = pkrtz(qa.x, qa.y); gq.y = pkrtz(qa.z, qa.w);
                            gq.z = pkrtz(qb.x, qb.y); gq.w = pkrtz(qb.z, qb.w);
                        }
                        H2U ma, ga;
                        ma.u = mv.x; ga.u = gq.x; o0 += ma.h * ga.h;
                        ma.u = mv.y; ga.u = gq.y; o1 += ma.h * ga.h;
                        ma.u = mv.z; ga.u = gq.z; o2 += ma.h * ga.h;
                        ma.u = mv.w; ga.u = gq.w; o3 += ma.h * ga.h;
                    }
                }
            }
            // reduce over ehalf partner (lane ^ 16), still packed f16
            H2U u0, u1, u2, u3, p;
            u0.h = o0; u1.h = o1; u2.h = o2; u3.h = o3;
            p.u = (unsigned int)__shfl_xor((int)u0.u, 16); u0.h += p.h;
            p.u = (unsigned int)__shfl_xor((int)u1.u, 16); u1.h += p.h;
            p.u = (unsigned int)__shfl_xor((int)u2.u, 16); u2.h += p.h;
            p.u = (unsigned int)__shfl_xor((int)u3.u, 16); u3.h += p.h;
            if (ehalf == 0) {
                const float invd = (dgs == 16) ? 0.0625f
                                 : 1.f / (float)(dgs > 0 ? dgs : 1);
                float* op = out + (size_t)bb*M*CC + (size_t)mw*CC + cchunk*8;
                float4 v0 = {(float)u0.h[0]*invd, (float)u0.h[1]*invd,
                             (float)u1.h[0]*invd, (float)u1.h[1]*invd};
                float4 v1 = {(float)u2.h[0]*invd, (float)u2.h[1]*invd,
                             (float)u3.h[0]*invd, (float)u3.h[1]*invd};
                *reinterpret_cast<float4*>(op)     = v0;
                *reinterpret_cast<float4*>(op + 4) = v1;
            }
        }
        // no trailing barrier: next-group writers (aggb via phase 0 after
        // this wave's own 2b; hb after barrier 1; msgb after barrier 2) are
        // all ordered w.r.t. every wave's reads above.
    }
}

extern "C" void kernel_launch(void* const* d_in, const int* in_sizes, int n_in,
                              void* d_out, int out_size, void* d_ws, size_t ws_size,
                              hipStream_t stream) {
    const float* x_in    = (const float*)d_in[0];
    const float* x_out   = (const float*)d_in[1];
    const float* in_feat = (const float*)d_in[2];
    const int*   nbr     = (const int*)d_in[3];
    const int*   rs      = (const int*)d_in[4];
    const float* W1      = (const float*)d_in[5];
    const float* b1      = (const float*)d_in[6];
    const float* W2      = (const float*)d_in[7];
    const float* b2      = (const float*)d_in[8];
    float* out = (float*)d_out;

    const int N = in_sizes[0] / 3;
    const int M = in_sizes[1] / 3;

    const int ngroups = (M + NB - 1) / NB;
    int grid = ngroups < 1024 ? ngroups : 1024;   // 4 blocks/CU persistent

    const size_t nfeat = (size_t)2 * N * CC;    // B=2 per reference
    const bool use_f16 = (ws_size >= nfeat * sizeof(_Float16)) &&
                         (nfeat % 8 == 0);
    if (use_f16) {
        const long n8 = (long)(nfeat / 8);
        int cgrid = (int)((n8 + 255) / 256);
        if (cgrid > 4096) cgrid = 4096;
        f32_to_f16_kernel<<<cgrid, 256, 0, stream>>>(
            in_feat, (_Float16*)d_ws, n8);
        nmlp_kernel<true><<<grid, 256, 0, stream>>>(
            x_in, x_out, in_feat, (const _Float16*)d_ws,
            nbr, rs, W1, b1, W2, b2, out, N, M);
    } else {
        nmlp_kernel<false><<<grid, 256, 0, stream>>>(
            x_in, x_out, in_feat, nullptr,
            nbr, rs, W1, b1, W2, b2, out, N, M);
    }
}